// Round 1
// baseline (4981.059 us; speedup 1.0000x reference)
//
#include <hip/hip_runtime.h>

// QRNN: T=512, B=32, D=1024, Q=256.
//  Phase A (prep):  build WhT/UhT fp16 [e][d] (transposed) from quaternion blocks; zero flags.
//  Phase B (gemm):  wh_out = x @ Wh + b  -> written fp32 into d_out (overwritten by scan).
//  Phase C (scan):  h_t = tanh(wh_out[t] + h_{t-1} @ Uh), in-place on d_out.
//                   64 WGs = 2 row-groups x 32 col-groups; flag sync within row group only.

#define TT 512
#define BB 32
#define DD 1024
#define QQ 256
#define MM (TT * BB)   // 16384

typedef _Float16 f16;
typedef _Float16 f16x8 __attribute__((ext_vector_type(8)));
typedef _Float16 f16x4 __attribute__((ext_vector_type(4)));
typedef float f32x4 __attribute__((ext_vector_type(4)));

// quaternion block tables: Wh[br*Q+i, bc*Q+j] = QSIGN[br][bc] * W_{QCOMP[br][bc]}[i][j]
__device__ __constant__ int   QCOMP[4][4] = {{0,1,2,3},{1,0,3,2},{2,3,0,1},{3,2,1,0}};
__device__ __constant__ float QSIGN[4][4] = {{ 1.f, 1.f, 1.f, 1.f},
                                             {-1.f, 1.f, 1.f,-1.f},
                                             {-1.f,-1.f, 1.f, 1.f},
                                             {-1.f, 1.f,-1.f, 1.f}};

__device__ __forceinline__ float qpick(int cmp, const float* a, const float* b,
                                       const float* c, const float* d, int idx) {
    const float* s = (cmp == 0) ? a : (cmp == 1) ? b : (cmp == 2) ? c : d;
    return s[idx];
}

// ---------------- Phase A: build WhT, UhT (fp16, transposed [e][d]), zero flags ----------
__global__ void qrnn_prep(const float* __restrict__ wr, const float* __restrict__ wi,
                          const float* __restrict__ wj, const float* __restrict__ wk,
                          const float* __restrict__ ur, const float* __restrict__ ui,
                          const float* __restrict__ uj, const float* __restrict__ uk,
                          f16* __restrict__ WhT, f16* __restrict__ UhT,
                          int* __restrict__ flags)
{
    int bid = blockIdx.x;
    int gid = bid * 256 + threadIdx.x;
    if (bid < 4096) {                    // WhT: 1M elements, flat = e*1024 + d
        int e = gid >> 10, d = gid & 1023;
        int bc = e >> 8, j = e & 255, br = d >> 8, i = d & 255;
        float v = QSIGN[br][bc] * qpick(QCOMP[br][bc], wr, wi, wj, wk, i * 256 + j);
        WhT[gid] = (f16)v;
    } else if (bid < 8192) {             // UhT
        int g = gid - 4096 * 256;
        int e = g >> 10, d = g & 1023;
        int bc = e >> 8, j = e & 255, br = d >> 8, i = d & 255;
        float v = QSIGN[br][bc] * qpick(QCOMP[br][bc], ur, ui, uj, uk, i * 256 + j);
        UhT[g] = (f16)v;
    } else {                             // flags: 2*512*32 = 32768 ints -> zero
        int g = gid - 8192 * 256;
        if (g < 2 * 512 * 32) flags[g] = 0;
    }
}

// ---------------- Phase B: wh_out = x @ Wh + bias  (fp32 out into d_out) ----------------
// 128x128 tile, BK=64, 256 threads = 4 waves, each wave a 64x64 quadrant (4x4 MFMA tiles).
__global__ __launch_bounds__(256) void qrnn_gemm(const float* __restrict__ x,
                                                 const f16* __restrict__ WhT,
                                                 const float* __restrict__ bias,
                                                 float* __restrict__ out)
{
    __shared__ f16 Ash[128][72];   // [m][k], +8 pad: ds_read_b128 at 2-way (free)
    __shared__ f16 Bsh[128][72];   // [n][k]

    const int tn = blockIdx.x, tm = blockIdx.y;
    const int tid = threadIdx.x;
    const int lane = tid & 63, w = tid >> 6;
    const int wm = (w >> 1) * 64, wn = (w & 1) * 64;
    const int m0 = tm * 128, n0 = tn * 128;
    const int l15 = lane & 15, q8 = (lane >> 4) * 8;

    f32x4 acc[4][4] = {};

    const int arow = tid >> 4;          // A staging: 16 rows/pass, float4 per thread
    const int acol = (tid & 15) * 4;
    const int brow = tid >> 3;          // B staging: 32 rows/pass, 8 halves per thread
    const int bcol = (tid & 7) * 8;

    for (int kb = 0; kb < DD; kb += 64) {
        // stage A (fp32 -> fp16 convert fused)
        #pragma unroll
        for (int p = 0; p < 8; ++p) {
            int rrow = p * 16 + arow;
            float4 v = *(const float4*)(x + (size_t)(m0 + rrow) * DD + kb + acol);
            f16x4 hv = {(f16)v.x, (f16)v.y, (f16)v.z, (f16)v.w};
            *(f16x4*)&Ash[rrow][acol] = hv;
        }
        // stage B (already fp16, [n][k] row-major slice)
        #pragma unroll
        for (int p = 0; p < 4; ++p) {
            int rn = p * 32 + brow;
            f16x8 v = *(const f16x8*)(WhT + (size_t)(n0 + rn) * DD + kb + bcol);
            *(f16x8*)&Bsh[rn][bcol] = v;
        }
        __syncthreads();
        #pragma unroll
        for (int ks = 0; ks < 64; ks += 32) {
            f16x8 af[4], bf[4];
            #pragma unroll
            for (int i = 0; i < 4; ++i) af[i] = *(const f16x8*)&Ash[wm + i * 16 + l15][ks + q8];
            #pragma unroll
            for (int i = 0; i < 4; ++i) bf[i] = *(const f16x8*)&Bsh[wn + i * 16 + l15][ks + q8];
            #pragma unroll
            for (int i = 0; i < 4; ++i)
                #pragma unroll
                for (int j = 0; j < 4; ++j)
                    acc[i][j] = __builtin_amdgcn_mfma_f32_16x16x32_f16(af[i], bf[j], acc[i][j], 0, 0, 0);
        }
        __syncthreads();
    }
    // epilogue: D layout col=lane&15, row=(lane>>4)*4+reg
    const int quad = lane >> 4;
    #pragma unroll
    for (int i = 0; i < 4; ++i)
        #pragma unroll
        for (int j = 0; j < 4; ++j) {
            int col = n0 + wn + j * 16 + l15;
            float bz = bias[col];
            #pragma unroll
            for (int rr = 0; rr < 4; ++rr) {
                int row = m0 + wm + i * 16 + quad * 4 + rr;
                out[(size_t)row * DD + col] = acc[i][j][rr] + bz;
            }
        }
}

// ---------------- Phase C: sequential scan ------------------------------------------
// 64 WGs x 128 threads (2 waves). WG (r,c): batch rows [16r,16r+16), cols [32c,32c+32).
// Wave w handles 16 cols. Uh slice preloaded into 128 VGPRs (constant over t).
// Sync: per (r,t,c) flag; consumer polls all 32 flags of its row group for step t-1.
__global__ __launch_bounds__(128, 1) void qrnn_scan(const f16* __restrict__ UhT,
                                                    f16* __restrict__ hbuf,
                                                    int* __restrict__ flags,
                                                    float* __restrict__ out)
{
    const int r = blockIdx.x >> 5;          // row group 0..1
    const int c = blockIdx.x & 31;          // col group 0..31
    const int tid = threadIdx.x;
    const int w = tid >> 6, lane = tid & 63;
    const int l15 = lane & 15, quad = lane >> 4, q8 = quad * 8;
    const int col0 = c * 32 + w * 16;
    const int dcol = col0 + l15;            // output feature col for D-frag
    const int bq = r * 16 + quad * 4;       // first output batch row for D-frag

    // preload B-frags (Uh slice for my 16 cols): 32 x f16x8 = 128 VGPRs, reused 512x
    const f16* ub = UhT + (size_t)dcol * DD + q8;   // B[k][n]: n=lane&15, k=quad*8+j
    f16x8 bfr[32];
    #pragma unroll
    for (int u = 0; u < 32; ++u) bfr[u] = *(const f16x8*)(ub + u * 32);

    const f16* habase = hbuf + (size_t)(r * 16 + l15) * DD + q8;  // A[m][k]: m=lane&15
    f16* hw = hbuf + (size_t)bq * DD + dcol;

    #pragma unroll 1
    for (int t = 0; t < TT; ++t) {
        const size_t obase = (size_t)t * (BB * DD) + (size_t)bq * DD + dcol;
        // prefetch wh tile (independent of flags)
        float wh[4];
        #pragma unroll
        for (int i = 0; i < 4; ++i) wh[i] = out[obase + i * DD];

        f32x4 acc = {0.f, 0.f, 0.f, 0.f};
        if (t > 0) {
            if (tid < 32) {
                int* fp = flags + ((r << 9) + (t - 1)) * 32 + tid;
                while (__hip_atomic_load(fp, __ATOMIC_RELAXED, __HIP_MEMORY_SCOPE_AGENT) == 0) {}
            }
            __syncthreads();
            __builtin_amdgcn_fence(__ATOMIC_ACQUIRE, "agent");

            const f16* ha = habase + (size_t)((t - 1) & 1) * (BB * DD);
            #pragma unroll
            for (int u = 0; u < 32; ++u) {
                f16x8 av = *(const f16x8*)(ha + u * 32);
                acc = __builtin_amdgcn_mfma_f32_16x16x32_f16(av, bfr[u], acc, 0, 0, 0);
            }
        }
        // epilogue: z = acc + wh; h = tanh(z); store fp32 (d_out) + fp16 (hbuf)
        f16* hwp = hw + (size_t)(t & 1) * (BB * DD);
        #pragma unroll
        for (int i = 0; i < 4; ++i) {
            float hv = tanhf(acc[i] + wh[i]);
            out[obase + i * DD] = hv;
            hwp[i * DD] = (f16)hv;
        }
        __builtin_amdgcn_fence(__ATOMIC_RELEASE, "agent");
        __syncthreads();
        if (tid == 0)
            __hip_atomic_store(flags + ((r << 9) + t) * 32 + c, 1,
                               __ATOMIC_RELAXED, __HIP_MEMORY_SCOPE_AGENT);
    }
}

extern "C" void kernel_launch(void* const* d_in, const int* in_sizes, int n_in,
                              void* d_out, int out_size, void* d_ws, size_t ws_size,
                              hipStream_t stream)
{
    const float* x  = (const float*)d_in[0];
    const float* wr = (const float*)d_in[1];
    const float* wi = (const float*)d_in[2];
    const float* wj = (const float*)d_in[3];
    const float* wk = (const float*)d_in[4];
    const float* ur = (const float*)d_in[5];
    const float* ui = (const float*)d_in[6];
    const float* uj = (const float*)d_in[7];
    const float* uk = (const float*)d_in[8];
    const float* bias = (const float*)d_in[9];
    float* out = (float*)d_out;

    char* ws = (char*)d_ws;
    f16* WhT  = (f16*)(ws);                       // 2 MB
    f16* UhT  = (f16*)(ws + (1 << 21));           // 2 MB
    f16* hbuf = (f16*)(ws + (1 << 22));           // 2 x 32 x 1024 fp16 = 128 KB
    int* flags = (int*)(ws + (1 << 22) + (1 << 17)); // 2*512*32 ints = 128 KB

    hipLaunchKernelGGL(qrnn_prep, dim3(8320), dim3(256), 0, stream,
                       wr, wi, wj, wk, ur, ui, uj, uk, WhT, UhT, flags);
    hipLaunchKernelGGL(qrnn_gemm, dim3(8, 128), dim3(256), 0, stream,
                       x, WhT, bias, out);
    hipLaunchKernelGGL(qrnn_scan, dim3(64), dim3(128), 0, stream,
                       UhT, hbuf, flags, out);
}

// Round 2
// 3237.642 us; speedup vs baseline: 1.5385x; 1.5385x over previous
//
#include <hip/hip_runtime.h>

// QRNN: T=512, B=32, D=1024, Q=256.
//  Phase A (prep):  build WhT/UhT fp16 [e][d] (transposed) from quaternion blocks; zero flags.
//  Phase B (gemm):  wh_out = x @ Wh + b  -> written fp32 into d_out (overwritten by scan).
//  Phase C (scan):  h_t = tanh(wh_out[t] + h_{t-1} @ Uh), in-place on d_out.
//      64 WGs = 2 row-groups x 32 col-groups; 128 thr/WG (2 waves x 16 cols).
//      NO agent fences (they compile to whole-L2 buffer_inv/buffer_wbl2 -> R1's 9.7us/step).
//      All inter-WG traffic via per-access coherent atomics (sc0 sc1 -> LLC).
//      Uh slice lives in LDS (R1: compiler refused to keep it in VGPRs; VGPR_Count=84).

#define TT 512
#define BB 32
#define DD 1024

typedef _Float16 f16;
typedef _Float16 f16x8 __attribute__((ext_vector_type(8)));
typedef _Float16 f16x4 __attribute__((ext_vector_type(4)));
typedef float f32x4 __attribute__((ext_vector_type(4)));

__device__ __constant__ int   QCOMP[4][4] = {{0,1,2,3},{1,0,3,2},{2,3,0,1},{3,2,1,0}};
__device__ __constant__ float QSIGN[4][4] = {{ 1.f, 1.f, 1.f, 1.f},
                                             {-1.f, 1.f, 1.f,-1.f},
                                             {-1.f,-1.f, 1.f, 1.f},
                                             {-1.f, 1.f,-1.f, 1.f}};

__device__ __forceinline__ float qpick(int cmp, const float* a, const float* b,
                                       const float* c, const float* d, int idx) {
    const float* s = (cmp == 0) ? a : (cmp == 1) ? b : (cmp == 2) ? c : d;
    return s[idx];
}

// ---------------- Phase A -------------------------------------------------------------
__global__ void qrnn_prep(const float* __restrict__ wr, const float* __restrict__ wi,
                          const float* __restrict__ wj, const float* __restrict__ wk,
                          const float* __restrict__ ur, const float* __restrict__ ui,
                          const float* __restrict__ uj, const float* __restrict__ uk,
                          f16* __restrict__ WhT, f16* __restrict__ UhT,
                          int* __restrict__ flags)
{
    int bid = blockIdx.x;
    int gid = bid * 256 + threadIdx.x;
    if (bid < 4096) {                    // WhT: 1M elements, flat = e*1024 + d
        int e = gid >> 10, d = gid & 1023;
        int bc = e >> 8, j = e & 255, br = d >> 8, i = d & 255;
        float v = QSIGN[br][bc] * qpick(QCOMP[br][bc], wr, wi, wj, wk, i * 256 + j);
        WhT[gid] = (f16)v;
    } else if (bid < 8192) {             // UhT
        int g = gid - 4096 * 256;
        int e = g >> 10, d = g & 1023;
        int bc = e >> 8, j = e & 255, br = d >> 8, i = d & 255;
        float v = QSIGN[br][bc] * qpick(QCOMP[br][bc], ur, ui, uj, uk, i * 256 + j);
        UhT[g] = (f16)v;
    } else {                             // flags: 2*512*32 = 32768 ints -> zero
        int g = gid - 8192 * 256;
        if (g < 2 * 512 * 32) flags[g] = 0;
    }
}

// ---------------- Phase B: wh_out = x @ Wh + bias ------------------------------------
__global__ __launch_bounds__(256) void qrnn_gemm(const float* __restrict__ x,
                                                 const f16* __restrict__ WhT,
                                                 const float* __restrict__ bias,
                                                 float* __restrict__ out)
{
    __shared__ f16 Ash[128][72];
    __shared__ f16 Bsh[128][72];

    const int tn = blockIdx.x, tm = blockIdx.y;
    const int tid = threadIdx.x;
    const int lane = tid & 63, w = tid >> 6;
    const int wm = (w >> 1) * 64, wn = (w & 1) * 64;
    const int m0 = tm * 128, n0 = tn * 128;
    const int l15 = lane & 15, q8 = (lane >> 4) * 8;

    f32x4 acc[4][4] = {};

    const int arow = tid >> 4;
    const int acol = (tid & 15) * 4;
    const int brow = tid >> 3;
    const int bcol = (tid & 7) * 8;

    for (int kb = 0; kb < DD; kb += 64) {
        #pragma unroll
        for (int p = 0; p < 8; ++p) {
            int rrow = p * 16 + arow;
            float4 v = *(const float4*)(x + (size_t)(m0 + rrow) * DD + kb + acol);
            f16x4 hv = {(f16)v.x, (f16)v.y, (f16)v.z, (f16)v.w};
            *(f16x4*)&Ash[rrow][acol] = hv;
        }
        #pragma unroll
        for (int p = 0; p < 4; ++p) {
            int rn = p * 32 + brow;
            f16x8 v = *(const f16x8*)(WhT + (size_t)(n0 + rn) * DD + kb + bcol);
            *(f16x8*)&Bsh[rn][bcol] = v;
        }
        __syncthreads();
        #pragma unroll
        for (int ks = 0; ks < 64; ks += 32) {
            f16x8 af[4], bf[4];
            #pragma unroll
            for (int i = 0; i < 4; ++i) af[i] = *(const f16x8*)&Ash[wm + i * 16 + l15][ks + q8];
            #pragma unroll
            for (int i = 0; i < 4; ++i) bf[i] = *(const f16x8*)&Bsh[wn + i * 16 + l15][ks + q8];
            #pragma unroll
            for (int i = 0; i < 4; ++i)
                #pragma unroll
                for (int j = 0; j < 4; ++j)
                    acc[i][j] = __builtin_amdgcn_mfma_f32_16x16x32_f16(af[i], bf[j], acc[i][j], 0, 0, 0);
        }
        __syncthreads();
    }
    const int quad = lane >> 4;
    #pragma unroll
    for (int i = 0; i < 4; ++i)
        #pragma unroll
        for (int j = 0; j < 4; ++j) {
            int col = n0 + wn + j * 16 + l15;
            float bz = bias[col];
            #pragma unroll
            for (int rr = 0; rr < 4; ++rr) {
                int row = m0 + wm + i * 16 + quad * 4 + rr;
                out[(size_t)row * DD + col] = acc[i][j][rr] + bz;
            }
        }
}

// ---------------- Phase C: sequential scan -------------------------------------------
// WG (r,c): batch rows [16r,16r+16), cols [32c,32c+32). Wave w: 16 cols.
// Uh slice in LDS (padded). h comm via coherent atomics through LLC; no fences.
__global__ __launch_bounds__(128, 1) void qrnn_scan(const f16* __restrict__ UhT,
                                                    unsigned int* __restrict__ hbuf,
                                                    int* __restrict__ flags,
                                                    float* __restrict__ out)
{
    __shared__ f16 Ush[32][1032];   // 32 cols x 1024 k, +8 pad (2-way bank alias = free)

    const int r = blockIdx.x >> 5;          // row group 0..1
    const int c = blockIdx.x & 31;          // col group 0..31
    const int tid = threadIdx.x;
    const int w = tid >> 6, lane = tid & 63;
    const int l15 = lane & 15, quad = lane >> 4, q8 = quad * 8;
    const int dcol = c * 32 + w * 16 + l15; // output feature col (D-frag n)
    const int bq = r * 16 + quad * 4;       // first output batch row (D-frag)

    // stage Uh slice -> LDS: each thread 256 halves of one row
    {
        const int nl = tid >> 2, k0 = (tid & 3) * 256;
        const f16* src = UhT + (size_t)(c * 32 + nl) * DD + k0;
        #pragma unroll
        for (int p = 0; p < 32; ++p)
            *(f16x8*)&Ush[nl][k0 + p * 8] = *(const f16x8*)(src + p * 8);
    }
    __syncthreads();

    const int nloc = w * 16 + l15;          // local col for B-frag reads

    // comm buffer geometry (fp16 elements addressed via u32/u64)
    // element idx = row*1024 + k ; byte = idx*2 ; buffers at parity*65536 bytes
    char* hb = (char*)hbuf;
    const char* harow = hb + (size_t)((r * 16 + l15) * 1024 + q8) * 2;  // A[m][k] m=l15
    char* hwrow = hb + (size_t)(bq * 1024 + (dcol & ~1)) * 2;           // packed u32 store base

    #pragma unroll 1
    for (int t = 0; t < TT; ++t) {
        const size_t obase = (size_t)t * (BB * DD) + (size_t)bq * DD + dcol;
        // prefetch wh tile (normal cached loads; independent of handshake)
        float wh[4];
        #pragma unroll
        for (int i = 0; i < 4; ++i) wh[i] = out[obase + i * DD];

        f32x4 acc0 = {0.f, 0.f, 0.f, 0.f}, acc1 = {0.f, 0.f, 0.f, 0.f};
        if (t > 0) {
            if (tid < 32) {
                int* fp = flags + ((r << 9) + (t - 1)) * 32 + tid;
                while (__hip_atomic_load(fp, __ATOMIC_RELAXED, __HIP_MEMORY_SCOPE_AGENT) == 0) {}
            }
            __syncthreads();   // drains poll loads; broadcasts "all flags set"

            const char* ha = harow + ((t - 1) & 1) * 65536;
            #pragma unroll
            for (int u = 0; u < 32; ++u) {
                union { unsigned long long q[2]; f16x8 v; } uu;
                uu.q[0] = __hip_atomic_load((const unsigned long long*)(ha + u * 64),
                                            __ATOMIC_RELAXED, __HIP_MEMORY_SCOPE_AGENT);
                uu.q[1] = __hip_atomic_load((const unsigned long long*)(ha + u * 64 + 8),
                                            __ATOMIC_RELAXED, __HIP_MEMORY_SCOPE_AGENT);
                f16x8 bf = *(const f16x8*)&Ush[nloc][u * 32 + q8];
                if (u & 1) acc1 = __builtin_amdgcn_mfma_f32_16x16x32_f16(uu.v, bf, acc1, 0, 0, 0);
                else       acc0 = __builtin_amdgcn_mfma_f32_16x16x32_f16(uu.v, bf, acc0, 0, 0, 0);
            }
        }
        // epilogue: h = tanh(acc + wh); fp32 -> d_out (cached), fp16 packed -> hbuf (coherent)
        char* hwp = hwrow + (t & 1) * 65536;
        #pragma unroll
        for (int i = 0; i < 4; ++i) {
            float z = acc0[i] + acc1[i] + wh[i];
            float e = __expf(2.0f * z);
            float hv = 1.0f - 2.0f * __builtin_amdgcn_rcpf(e + 1.0f);
            out[obase + i * DD] = hv;
            f16 hh = (f16)hv;
            unsigned short hbits = __builtin_bit_cast(unsigned short, hh);
            int other = __shfl_xor((int)hbits, 1, 64);   // partner col (l15 ^ 1)
            if ((lane & 1) == 0) {
                unsigned int packed = (unsigned int)hbits | ((unsigned int)other << 16);
                __hip_atomic_store((unsigned int*)(hwp + (size_t)i * 2048), packed,
                                   __ATOMIC_RELAXED, __HIP_MEMORY_SCOPE_AGENT);
            }
        }
        asm volatile("s_waitcnt vmcnt(0)" ::: "memory");  // per-wave drain of coherent stores
        __syncthreads();                                   // all waves drained
        if (tid == 0)
            __hip_atomic_store(flags + ((r << 9) + t) * 32 + c, 1,
                               __ATOMIC_RELAXED, __HIP_MEMORY_SCOPE_AGENT);
    }
}

extern "C" void kernel_launch(void* const* d_in, const int* in_sizes, int n_in,
                              void* d_out, int out_size, void* d_ws, size_t ws_size,
                              hipStream_t stream)
{
    const float* x  = (const float*)d_in[0];
    const float* wr = (const float*)d_in[1];
    const float* wi = (const float*)d_in[2];
    const float* wj = (const float*)d_in[3];
    const float* wk = (const float*)d_in[4];
    const float* ur = (const float*)d_in[5];
    const float* ui = (const float*)d_in[6];
    const float* uj = (const float*)d_in[7];
    const float* uk = (const float*)d_in[8];
    const float* bias = (const float*)d_in[9];
    float* out = (float*)d_out;

    char* ws = (char*)d_ws;
    f16* WhT  = (f16*)(ws);                          // 2 MB
    f16* UhT  = (f16*)(ws + (1 << 21));              // 2 MB
    unsigned int* hbuf = (unsigned int*)(ws + (1 << 22));      // 2 x 64 KB
    int* flags = (int*)(ws + (1 << 22) + (1 << 17)); // 32768 ints

    hipLaunchKernelGGL(qrnn_prep, dim3(8320), dim3(256), 0, stream,
                       wr, wi, wj, wk, ur, ui, uj, uk, WhT, UhT, flags);
    hipLaunchKernelGGL(qrnn_gemm, dim3(8, 128), dim3(256), 0, stream,
                       x, WhT, bias, out);
    hipLaunchKernelGGL(qrnn_scan, dim3(64), dim3(128), 0, stream,
                       UhT, hbuf, flags, out);
}